// Round 3
// baseline (361.832 us; speedup 1.0000x reference)
//
#include <hip/hip_runtime.h>
#include <math.h>
#include <stdint.h>

#define POS_W 1.0f
#define ANG_W 1.0f
#define WID_W 1.0f
#define CHUNK 1024         // target rows per LDS chunk
#define F4PT 6             // (CHUNK*3/2)/256 float4 per thread per chunk

__device__ __forceinline__ float smooth_l1(float x) {
    float a = fabsf(x);
    return a < 1.0f ? 0.5f * x * x : a - 0.5f;
}

// Barrier WITHOUT the __syncthreads vmcnt(0) drain. LDS producer/consumer
// ordering only needs lgkmcnt(0); global prefetch loads (thread-private
// registers) may stay in flight across the barrier. sched_barrier(0) pins
// codegen from hoisting ds ops across (guide rule #18).
__device__ __forceinline__ void bar_lds() {
    asm volatile("s_waitcnt lgkmcnt(0)" ::: "memory");
    __builtin_amdgcn_s_barrier();
    __builtin_amdgcn_sched_barrier(0);
}

// ---------------------------------------------------------------------------
// Kernel A: per-block (256 counts) sums. blockSums is 16 KB; kernel B derives
// each block's exclusive prefix from it out of L2/LLC.
// ---------------------------------------------------------------------------
__global__ void k_block_sums(const int* __restrict__ counts, int stride, int n,
                             int* __restrict__ blockSums) {
    int i = blockIdx.x * 256 + threadIdx.x;
    int c = (i < n) ? counts[(long long)i * stride] : 0;
    for (int off = 32; off > 0; off >>= 1) c += __shfl_down(c, off, 64);
    __shared__ int sdata[4];
    int lane = threadIdx.x & 63, wave = threadIdx.x >> 6;
    if (lane == 0) sdata[wave] = c;
    __syncthreads();
    if (threadIdx.x == 0)
        blockSums[blockIdx.x] = sdata[0] + sdata[1] + sdata[2] + sdata[3];
}

// ---------------------------------------------------------------------------
// Kernel B: one thread per prediction. Per-block exclusive prefix from
// blockSums (L2-hit loads + wave reduce). Target window staged through LDS in
// CHUNK-row pieces with float4 (16 B/lane) register-batched loads, align-down
// shift for the 24 B-granular window start, and vmcnt-drain-free barriers so
// next-chunk prefetch latency hides under compute + other blocks.
// ---------------------------------------------------------------------------
__global__ __launch_bounds__(256) void k_loss(
    const float* __restrict__ pred, const float* __restrict__ tgt,
    const int* __restrict__ counts, int stride, int n, int mrows,
    const int* __restrict__ blockSums, float invN, float* __restrict__ out) {
    __shared__ float4 ch4[CHUNK * 3 / 2 + 1];  // 24.6 KB (+1 f4 slack for sh)
    __shared__ int wsum[4];
    __shared__ int wpre[4];
    __shared__ float fs[4];

    int t = threadIdx.x;
    int lane = t & 63, wave = t >> 6;
    int b = blockIdx.x;
    int i = b * 256 + t;
    int c = (i < n) ? counts[(long long)i * stride] : 0;

    // per-thread partial of exclusive block prefix: sum blockSums[0..b)
    int pre = 0;
    for (int j = t; j < b; j += 256) pre += blockSums[j];

    // wave-level inclusive scan of counts (no barriers)
    int incl = c;
#pragma unroll
    for (int d = 1; d < 64; d <<= 1) {
        int v = __shfl_up(incl, d, 64);
        if (lane >= d) incl += v;
    }
    for (int o = 32; o > 0; o >>= 1) pre += __shfl_down(pre, o, 64);
    if (lane == 63) wsum[wave] = incl;
    if (lane == 0) wpre[wave] = pre;
    __syncthreads();

    int w0 = wsum[0], w1 = wsum[1], w2 = wsum[2], w3 = wsum[3];
    int waveOff = (wave > 0 ? w0 : 0) + (wave > 1 ? w1 : 0) + (wave > 2 ? w2 : 0);
    int off = waveOff + incl - c;       // exclusive prefix within block
    int total = w0 + w1 + w2 + w3;      // rows this block consumes
    int winStart = wpre[0] + wpre[1] + wpre[2] + wpre[3];

    // pred loads AFTER the scan barrier: pipeline with chunk-0 staging loads
    bool active = (i < n) && (c > 0);
    float p0 = 0, p1 = 0, p2 = 0, p3 = 0, p4 = 0;
    if (active) {
        const float2* p2p = (const float2*)(pred + (long long)i * 6);
        float2 a = p2p[0], bb = p2p[1], w = p2p[2];
        p0 = a.x; p1 = a.y; p2 = bb.x; p3 = bb.y; p4 = w.x;
    }

    // window base, aligned down to 16 B; sh = 1 if window starts 8 B into f4
    long long winB = (long long)winStart * 24;
    long long alignedB = winB & ~15ll;
    const float4* win4 = (const float4*)((const char*)tgt + alignedB);
    int sh = (int)(winStart & 1);  // winStart*24 mod 16 == 8 iff winStart odd
    // f4s available from aligned base to array end (array end is 16-aligned)
    int f4maxi = (int)(((long long)mrows * 24 - alignedB) >> 4);

    float best = INFINITY;
    float b0 = 0, b1 = 0, b2 = 0, b3 = 0, b4 = 0;
    const float2* ch2 = (const float2*)ch4;
    float4 rf[F4PT];

    // prologue: prefetch chunk 0 into registers
    {
        int rows0 = min(CHUNK, total);
        int nF4 = (rows0 * 3 + sh + 1) >> 1;
        int lim = min(nF4, f4maxi);
#pragma unroll
        for (int j = 0; j < F4PT; ++j) {
            int q = t + 256 * j;
            if (q < lim) rf[j] = win4[q];
        }
    }

    for (int base = 0; base < total; base += CHUNK) {
        int rows = min(CHUNK, total - base);
        int nF4c = (rows * 3 + sh + 1) >> 1;
        int qB = (base * 3) >> 1;             // base*3 is even (CHUNK even)
        int lim = min(nF4c, f4maxi - qB);
        // registers -> LDS (ds_write waits on its own load via register dep)
#pragma unroll
        for (int j = 0; j < F4PT; ++j) {
            int q = t + 256 * j;
            if (q < lim) ch4[q] = rf[j];
        }
        bar_lds();  // writes visible; prefetch (none yet) not drained
        // prefetch next chunk while computing this one
        int nbase = base + CHUNK;
        if (nbase < total) {
            int rowsn = min(CHUNK, total - nbase);
            int nF4n = (rowsn * 3 + sh + 1) >> 1;
            int qBn = (nbase * 3) >> 1;
            int limn = min(nF4n, f4maxi - qBn);
#pragma unroll
            for (int j = 0; j < F4PT; ++j) {
                int q = t + 256 * j;
                if (q < limn) rf[j] = win4[qBn + q];
            }
        }
        if (active) {
            int lo = max(off, base), hi = min(off + c, base + rows);
            for (int rr = lo; rr < hi; ++rr) {
                int l2i = (rr - base) * 3 + sh;
                float2 ga = ch2[l2i], gb = ch2[l2i + 1], gw = ch2[l2i + 2];
                float d0 = p0 - ga.x, d1 = p1 - ga.y;
                float d2 = p2 - gb.x, d3 = p3 - gb.y;
                float d4 = p4 - gw.x;
                float dist = POS_W * (d0 * d0 + d1 * d1) +
                             ANG_W * (d2 * d2 + d3 * d3) + WID_W * d4 * d4;
                if (dist < best) {  // strict <: first occurrence, matches ref
                    best = dist;
                    b0 = ga.x; b1 = ga.y; b2 = gb.x; b3 = gb.y; b4 = gw.x;
                }
            }
        }
        bar_lds();  // reads retired before next overwrite; NO vmcnt drain ->
                    // next-chunk prefetch stays in flight across the barrier
    }

    float loss = 0.0f;
    if (active) {
        loss = POS_W * (smooth_l1(p0 - b0) + smooth_l1(p1 - b1)) +
               ANG_W * (fabsf(p2 - b2) + fabsf(p3 - b3)) +
               WID_W * smooth_l1(p4 - b4);
    }

    for (int o = 32; o > 0; o >>= 1) loss += __shfl_down(loss, o, 64);
    if (lane == 0) fs[wave] = loss;
    __syncthreads();
    if (t == 0) {
        float tot = (fs[0] + fs[1] + fs[2] + fs[3]) * invN;
        atomicAdd(out, tot);
    }
}

// ---------------------------------------------------------------------------
extern "C" void kernel_launch(void* const* d_in, const int* in_sizes, int n_in,
                              void* d_out, int out_size, void* d_ws,
                              size_t ws_size, hipStream_t stream) {
    const float* pred = (const float*)d_in[0];
    const float* tgt = (const float*)d_in[1];
    const int* counts = (const int*)d_in[2];
    int n = in_sizes[0] / 6;
    int mrows = in_sizes[1] / 6;
    int stride = (in_sizes[2] == n) ? 1 : 2;  // int64 counts -> read low words
    int nb = (n + 255) / 256;

    int* blockSums = (int*)d_ws;
    float* out = (float*)d_out;

    hipMemsetAsync(d_out, 0, sizeof(float), stream);
    k_block_sums<<<nb, 256, 0, stream>>>(counts, stride, n, blockSums);
    k_loss<<<nb, 256, 0, stream>>>(pred, tgt, counts, stride, n, mrows,
                                   blockSums, 1.0f / n, out);
}

// Round 4
// 314.357 us; speedup vs baseline: 1.1510x; 1.1510x over previous
//
#include <hip/hip_runtime.h>
#include <math.h>
#include <stdint.h>

#define POS_W 1.0f
#define ANG_W 1.0f
#define WID_W 1.0f
#define CHUNK 682          // rows per LDS chunk: 682*3 f2 = 1023 f4 (+sh -> 1024)
#define SEGS 16            // 16 x 1KB global_load_lds segments per chunk
#define SEGS_PER_WAVE 4    // uniform per-wave issue count -> exact vmcnt(4)

__device__ __forceinline__ float smooth_l1(float x) {
    float a = fabsf(x);
    return a < 1.0f ? 0.5f * x * x : a - 0.5f;
}

// direct HBM->LDS DMA, 16 B per lane, no VGPR staging (nothing to spill).
// LDS dest = wave-uniform base + lane*16; global src is per-lane.
__device__ __forceinline__ void gl_lds16(const float4* g, float4* l) {
    __builtin_amdgcn_global_load_lds(
        (const __attribute__((address_space(1))) void*)g,
        (__attribute__((address_space(3))) void*)l, 16, 0, 0);
}

// ---------------------------------------------------------------------------
// Kernel A: per-block (256 counts) sums. blockSums is 16 KB; kernel B derives
// each block's exclusive prefix from it out of L2/LLC.
// ---------------------------------------------------------------------------
__global__ void k_block_sums(const int* __restrict__ counts, int stride, int n,
                             int* __restrict__ blockSums) {
    int i = blockIdx.x * 256 + threadIdx.x;
    int c = (i < n) ? counts[(long long)i * stride] : 0;
    for (int off = 32; off > 0; off >>= 1) c += __shfl_down(c, off, 64);
    __shared__ int sdata[4];
    int lane = threadIdx.x & 63, wave = threadIdx.x >> 6;
    if (lane == 0) sdata[wave] = c;
    __syncthreads();
    if (threadIdx.x == 0)
        blockSums[blockIdx.x] = sdata[0] + sdata[1] + sdata[2] + sdata[3];
}

// ---------------------------------------------------------------------------
// Kernel B: one thread per prediction. Per-block exclusive prefix recomputed
// from blockSums (L2-hit loads + wave reduce). Target window streamed through
// a 2-buffer LDS pipeline via global_load_lds (16 B granules, 1 KB/issue),
// counted s_waitcnt vmcnt(4) so next-chunk DMA stays in flight across the
// barrier (no __syncthreads vmcnt(0) drain; T3/T4 pattern).
// ---------------------------------------------------------------------------
__global__ __launch_bounds__(256) void k_loss(
    const float* __restrict__ pred, const float* __restrict__ tgt,
    const int* __restrict__ counts, int stride, int n, int mrows,
    const int* __restrict__ blockSums, float invN, float* __restrict__ out) {
    __shared__ float4 bufs[2][SEGS * 64];  // 2 x 16 KB
    __shared__ int wsum[4];
    __shared__ int wpre[4];
    __shared__ float fs[4];

    int t = threadIdx.x;
    int lane = t & 63, wave = t >> 6;
    int b = blockIdx.x;
    int i = b * 256 + t;
    int c = (i < n) ? counts[(long long)i * stride] : 0;

    // per-thread partial of exclusive block prefix: sum blockSums[0..b)
    int pre = 0;
    for (int j = t; j < b; j += 256) pre += blockSums[j];

    // wave-level inclusive scan of counts (no barriers)
    int incl = c;
#pragma unroll
    for (int d = 1; d < 64; d <<= 1) {
        int v = __shfl_up(incl, d, 64);
        if (lane >= d) incl += v;
    }
    for (int o = 32; o > 0; o >>= 1) pre += __shfl_down(pre, o, 64);
    if (lane == 63) wsum[wave] = incl;
    if (lane == 0) wpre[wave] = pre;
    __syncthreads();

    int w0 = wsum[0], w1 = wsum[1], w2 = wsum[2], w3 = wsum[3];
    int waveOff = (wave > 0 ? w0 : 0) + (wave > 1 ? w1 : 0) + (wave > 2 ? w2 : 0);
    int off = waveOff + incl - c;       // exclusive prefix within block
    int total = w0 + w1 + w2 + w3;      // rows this block consumes
    int winStart = wpre[0] + wpre[1] + wpre[2] + wpre[3];

    // pred loads: issue here; latency hides under chunk-0 DMA
    bool active = (i < n) && (c > 0);
    float p0 = 0, p1 = 0, p2 = 0, p3 = 0, p4 = 0;
    if (active) {
        const float2* p2p = (const float2*)(pred + (long long)i * 6);
        float2 a = p2p[0], bb = p2p[1], w = p2p[2];
        p0 = a.x; p1 = a.y; p2 = bb.x; p3 = bb.y; p4 = w.x;
    }

    // window geometry: align start down to 16 B; sh=1 if start is 8 B into f4
    long long winB = (long long)winStart * 24;
    long long alignedB = winB & ~15ll;
    long long base4 = alignedB >> 4;            // absolute f4 idx of window
    int sh = (int)(winStart & 1);
    long long f4last = (((long long)mrows * 24) >> 4) - 1;  // last valid f4
    const float4* tgt4 = (const float4*)tgt;

    // issue one chunk's 16 segments: wave w takes segs {w, w+4, w+8, w+12}
    auto issue_chunk = [&](int bi, int chunkBase) {
        long long q0 = base4 + (((long long)chunkBase * 3) >> 1);
#pragma unroll
        for (int k = 0; k < SEGS_PER_WAVE; ++k) {
            int seg = wave + 4 * k;
            long long gi = q0 + seg * 64 + lane;
            if (gi > f4last) gi = f4last;   // clamp: same-line dup, no OOB
            gl_lds16(tgt4 + gi, &bufs[bi][seg * 64]);
        }
    };

    float best = INFINITY;
    float b0 = 0, b1 = 0, b2 = 0, b3 = 0, b4 = 0;

    if (total > 0) issue_chunk(0, 0);   // prologue DMA for chunk 0

    int cur = 0;
    for (int base = 0; base < total; base += CHUNK, cur ^= 1) {
        int nbase = base + CHUNK;
        if (nbase < total) {
            issue_chunk(cur ^ 1, nbase);            // prefetch next chunk
            asm volatile("s_waitcnt vmcnt(4)" ::: "memory");  // cur landed,
                                                    // next 4 stay in flight
        } else {
            asm volatile("s_waitcnt vmcnt(0)" ::: "memory");
        }
        __builtin_amdgcn_s_barrier();
        __builtin_amdgcn_sched_barrier(0);

        if (active) {
            int rows = min(CHUNK, total - base);
            const float2* ch2 = (const float2*)&bufs[cur][0];
            int lo = max(off, base), hi = min(off + c, base + rows);
            for (int rr = lo; rr < hi; ++rr) {
                int l2i = (rr - base) * 3 + sh;
                float2 ga = ch2[l2i], gb = ch2[l2i + 1], gw = ch2[l2i + 2];
                float d0 = p0 - ga.x, d1 = p1 - ga.y;
                float d2 = p2 - gb.x, d3 = p3 - gb.y;
                float d4 = p4 - gw.x;
                float dist = POS_W * (d0 * d0 + d1 * d1) +
                             ANG_W * (d2 * d2 + d3 * d3) + WID_W * d4 * d4;
                if (dist < best) {  // strict <: first occurrence, matches ref
                    best = dist;
                    b0 = ga.x; b1 = ga.y; b2 = gb.x; b3 = gb.y; b4 = gw.x;
                }
            }
        }
        asm volatile("s_waitcnt lgkmcnt(0)" ::: "memory");
        __builtin_amdgcn_s_barrier();     // all reads retired before overwrite
        __builtin_amdgcn_sched_barrier(0);
    }

    float loss = 0.0f;
    if (active) {
        loss = POS_W * (smooth_l1(p0 - b0) + smooth_l1(p1 - b1)) +
               ANG_W * (fabsf(p2 - b2) + fabsf(p3 - b3)) +
               WID_W * smooth_l1(p4 - b4);
    }

    for (int o = 32; o > 0; o >>= 1) loss += __shfl_down(loss, o, 64);
    if (lane == 0) fs[wave] = loss;
    __syncthreads();
    if (t == 0) {
        float tot = (fs[0] + fs[1] + fs[2] + fs[3]) * invN;
        atomicAdd(out, tot);
    }
}

// ---------------------------------------------------------------------------
extern "C" void kernel_launch(void* const* d_in, const int* in_sizes, int n_in,
                              void* d_out, int out_size, void* d_ws,
                              size_t ws_size, hipStream_t stream) {
    const float* pred = (const float*)d_in[0];
    const float* tgt = (const float*)d_in[1];
    const int* counts = (const int*)d_in[2];
    int n = in_sizes[0] / 6;
    int mrows = in_sizes[1] / 6;
    int stride = (in_sizes[2] == n) ? 1 : 2;  // int64 counts -> read low words
    int nb = (n + 255) / 256;

    int* blockSums = (int*)d_ws;
    float* out = (float*)d_out;

    hipMemsetAsync(d_out, 0, sizeof(float), stream);
    k_block_sums<<<nb, 256, 0, stream>>>(counts, stride, n, blockSums);
    k_loss<<<nb, 256, 0, stream>>>(pred, tgt, counts, stride, n, mrows,
                                   blockSums, 1.0f / n, out);
}

// Round 5
// 302.999 us; speedup vs baseline: 1.1942x; 1.0375x over previous
//
#include <hip/hip_runtime.h>
#include <math.h>
#include <stdint.h>

#define POS_W 1.0f
#define ANG_W 1.0f
#define WID_W 1.0f
#define CHUNKR 2176   // rows per staging pass; >= max per-block total (2056)
#define SEGMAX 52     // LDS capacity in 1KB f4 segments: 52 KB

__device__ __forceinline__ float smooth_l1(float x) {
    float a = fabsf(x);
    return a < 1.0f ? 0.5f * x * x : a - 0.5f;
}

// direct HBM->LDS DMA, 16 B/lane, no VGPR staging (nothing to spill).
// LDS dest = wave-uniform base + lane*16; global src is per-lane.
__device__ __forceinline__ void gl_lds16(const float4* g, float4* l) {
    __builtin_amdgcn_global_load_lds(
        (const __attribute__((address_space(1))) void*)g,
        (__attribute__((address_space(3))) void*)l, 16, 0, 0);
}

// ---------------------------------------------------------------------------
// Kernel A: per-block (256 counts) sums. blockSums is 16 KB; kernel B derives
// each block's exclusive prefix from it out of L2/LLC.
// ---------------------------------------------------------------------------
__global__ void k_block_sums(const int* __restrict__ counts, int stride, int n,
                             int* __restrict__ blockSums) {
    int i = blockIdx.x * 256 + threadIdx.x;
    int c = (i < n) ? counts[(long long)i * stride] : 0;
    for (int off = 32; off > 0; off >>= 1) c += __shfl_down(c, off, 64);
    __shared__ int sdata[4];
    int lane = threadIdx.x & 63, wave = threadIdx.x >> 6;
    if (lane == 0) sdata[wave] = c;
    __syncthreads();
    if (threadIdx.x == 0)
        blockSums[blockIdx.x] = sdata[0] + sdata[1] + sdata[2] + sdata[3];
}

// ---------------------------------------------------------------------------
// Kernel B: one thread per prediction. The block's whole contiguous target
// window (<=2056 rows for this data) is staged in ONE global_load_lds volley
// into a single 52 KB buffer: one vmcnt(0)+barrier, short LDS compute, done.
// DMA-bound by design; latency hidden by 3 resident blocks/CU. Generic
// chunk-loop fallback keeps arbitrary count distributions correct.
// ---------------------------------------------------------------------------
__global__ __launch_bounds__(256) void k_loss(
    const float* __restrict__ pred, const float* __restrict__ tgt,
    const int* __restrict__ counts, int stride, int n, int mrows,
    const int* __restrict__ blockSums, float invN, float* __restrict__ out) {
    __shared__ float4 buf[SEGMAX * 64];  // 52 KB -> 3 blocks/CU
    __shared__ int wsum[4];
    __shared__ int wpre[4];
    __shared__ float fs[4];

    int t = threadIdx.x;
    int lane = t & 63, wave = t >> 6;
    int b = blockIdx.x;
    int i = b * 256 + t;
    int c = (i < n) ? counts[(long long)i * stride] : 0;

    // per-thread partial of exclusive block prefix: sum blockSums[0..b)
    int pre = 0;
    for (int j = t; j < b; j += 256) pre += blockSums[j];

    // wave-level inclusive scan of counts (no barriers)
    int incl = c;
#pragma unroll
    for (int d = 1; d < 64; d <<= 1) {
        int v = __shfl_up(incl, d, 64);
        if (lane >= d) incl += v;
    }
    for (int o = 32; o > 0; o >>= 1) pre += __shfl_down(pre, o, 64);
    if (lane == 63) wsum[wave] = incl;
    if (lane == 0) wpre[wave] = pre;

    // pred loads: issue early; latency hides under scan barrier + DMA
    bool active = (i < n) && (c > 0);
    float p0 = 0, p1 = 0, p2 = 0, p3 = 0, p4 = 0;
    if (active) {
        const float2* p2p = (const float2*)(pred + (long long)i * 6);
        float2 a = p2p[0], bb = p2p[1], w = p2p[2];
        p0 = a.x; p1 = a.y; p2 = bb.x; p3 = bb.y; p4 = w.x;
    }
    __syncthreads();

    int w0 = wsum[0], w1 = wsum[1], w2 = wsum[2], w3 = wsum[3];
    int waveOff = (wave > 0 ? w0 : 0) + (wave > 1 ? w1 : 0) + (wave > 2 ? w2 : 0);
    int off = waveOff + incl - c;       // exclusive prefix within block
    int total = w0 + w1 + w2 + w3;      // rows this block consumes
    int winStart = wpre[0] + wpre[1] + wpre[2] + wpre[3];

    // window geometry: align start down to 16 B; sh=1 if start is 8 B into f4
    long long winB = (long long)winStart * 24;
    long long base4 = (winB & ~15ll) >> 4;      // absolute f4 idx of window
    int sh = (int)(winStart & 1);
    long long f4last = (((long long)mrows * 24) >> 4) - 1;  // last valid f4
    const float4* tgt4 = (const float4*)tgt;
    const float2* ch2 = (const float2*)buf;

    float best = INFINITY;
    float b0 = 0, b1 = 0, b2 = 0, b3 = 0, b4 = 0;

    for (int base = 0; base < total; base += CHUNKR) {
        int rows = min(CHUNKR, total - base);
        int nF4 = (rows * 3 + sh + 1) >> 1;
        int nSeg = (nF4 + 63) >> 6;             // 1KB segments this pass
        long long q0 = base4 + (((long long)base * 3) >> 1);  // base*3 even
        for (int seg = wave; seg < nSeg; seg += 4) {
            long long gi = q0 + (long long)(seg << 6) + lane;
            if (gi > f4last) gi = f4last;       // clamp: same-line dup, no OOB
            gl_lds16(tgt4 + gi, &buf[seg * 64]);
        }
        asm volatile("s_waitcnt vmcnt(0)" ::: "memory");
        __builtin_amdgcn_s_barrier();
        __builtin_amdgcn_sched_barrier(0);

        if (active) {
            int lo = max(off, base), hi = min(off + c, base + rows);
            for (int rr = lo; rr < hi; ++rr) {
                int l2i = (rr - base) * 3 + sh;
                float2 ga = ch2[l2i], gb = ch2[l2i + 1], gw = ch2[l2i + 2];
                float d0 = p0 - ga.x, d1 = p1 - ga.y;
                float d2 = p2 - gb.x, d3 = p3 - gb.y;
                float d4 = p4 - gw.x;
                float dist = POS_W * (d0 * d0 + d1 * d1) +
                             ANG_W * (d2 * d2 + d3 * d3) + WID_W * d4 * d4;
                if (dist < best) {  // strict <: first occurrence, matches ref
                    best = dist;
                    b0 = ga.x; b1 = ga.y; b2 = gb.x; b3 = gb.y; b4 = gw.x;
                }
            }
        }
        if (base + CHUNKR < total) {  // generic multi-pass fallback only
            asm volatile("s_waitcnt lgkmcnt(0)" ::: "memory");
            __builtin_amdgcn_s_barrier();
            __builtin_amdgcn_sched_barrier(0);
        }
    }

    float loss = 0.0f;
    if (active) {
        loss = POS_W * (smooth_l1(p0 - b0) + smooth_l1(p1 - b1)) +
               ANG_W * (fabsf(p2 - b2) + fabsf(p3 - b3)) +
               WID_W * smooth_l1(p4 - b4);
    }

    for (int o = 32; o > 0; o >>= 1) loss += __shfl_down(loss, o, 64);
    if (lane == 0) fs[wave] = loss;
    __syncthreads();
    if (t == 0) {
        float tot = (fs[0] + fs[1] + fs[2] + fs[3]) * invN;
        atomicAdd(out, tot);
    }
}

// ---------------------------------------------------------------------------
extern "C" void kernel_launch(void* const* d_in, const int* in_sizes, int n_in,
                              void* d_out, int out_size, void* d_ws,
                              size_t ws_size, hipStream_t stream) {
    const float* pred = (const float*)d_in[0];
    const float* tgt = (const float*)d_in[1];
    const int* counts = (const int*)d_in[2];
    int n = in_sizes[0] / 6;
    int mrows = in_sizes[1] / 6;
    int stride = (in_sizes[2] == n) ? 1 : 2;  // int64 counts -> read low words
    int nb = (n + 255) / 256;

    int* blockSums = (int*)d_ws;
    float* out = (float*)d_out;

    hipMemsetAsync(d_out, 0, sizeof(float), stream);
    k_block_sums<<<nb, 256, 0, stream>>>(counts, stride, n, blockSums);
    k_loss<<<nb, 256, 0, stream>>>(pred, tgt, counts, stride, n, mrows,
                                   blockSums, 1.0f / n, out);
}